// Round 10
// baseline (181.545 us; speedup 1.0000x reference)
//
#include <hip/hip_runtime.h>
#include <stdint.h>

// ---------------------------------------------------------------------------
// MultiScaleGRU fused pipeline (MI355X / gfx950)
//
//   gi = (A @ C) @ w_ih^T + b_ih      A: [16384,4096] fp32 (attention_weights)
//   gh = h @ w_hh^T + b_hh            h: repeat(C[:16], 4)  -> [64,256]
//   r,z = sigmoid(gi_rz + gh_rz); n = tanh(gi_n + r*gh_n)
//   h_new = (1-z)*n + z*h ; out[o,b,:] = mean_j h_new[b, 4o+j, :]
//
// Numerics (passing, absmax 0.0156 vs 7.5e-2): single fp16 path. A centered
// (a-0.5, fp16 RNE) with exact fp32 csW[n]=sum_h 0.5*colsum(C)[h]*w_ih[n,h]
// folded into the stage-2 bias. MFMA order per acc element unchanged.
//
// R10 stage1 restructure (T3+T4): R9 still drained vmcnt(0) per K-step
// (m233 regime: stage+drain+barrier ~72% of iter). Now: BM=64, grid 256
// (1 block/CU), 512 thr (8 waves 2Mx4N); B TRIPLE-buffered (96 KB) +
// A dbuf (16 KB); per iter ONE barrier with counted vmcnt(6) -- B(k+1),
// A(k+1) stay in flight across the barrier; prefetch issued 2 tiles deep
// (~2400 cy slack > L3 ~900 cy). Never vmcnt(0) in the main loop.
// ---------------------------------------------------------------------------

typedef _Float16 half8 __attribute__((ext_vector_type(8)));
typedef float f32x4 __attribute__((ext_vector_type(4)));

// workspace layout (bytes)
#define WS_CT   0u          // Ct  : fp16 [256][4096] swz   (2 MB)
#define WS_WP   2097152u    // Wp  : fp16 [768][256]  swz   (384 KB)
#define WS_GH   2490368u    // GH  : f32  [64][768]         (192 KB)
#define WS_CSP  2686976u    // csum partials: f32 [16][256] (16 KB)
#define WS_CS   2703360u    // cs  : f32 [256]              (1 KB)
#define WS_CSW  2704384u    // csW : f32 [768]              (3 KB)
#define WS_X    2707456u    // X   : fp16 [16384][256] swz  (8 MB)
// total 11,096,064 bytes

static __device__ __forceinline__ _Float16 f2h(float x) {
  return (_Float16)x;  // v_cvt_f16_f32, RNE
}
static __device__ __forceinline__ void gload16(const void* g, void* lds) {
  // async global->LDS, 16B/lane; LDS dest = wave-uniform base + lane*16
  __builtin_amdgcn_global_load_lds(
      (const __attribute__((address_space(1))) unsigned int*)g,
      (__attribute__((address_space(3))) unsigned int*)lds, 16, 0, 0);
}
static __device__ __forceinline__ float sigmf(float x) {
  float e = __expf(-fabsf(x));
  float p = 1.f / (1.f + e);
  return x >= 0.f ? p : 1.f - p;
}
static __device__ __forceinline__ float tanhf2(float x) {
  float e = __expf(-2.f * fabsf(x));
  float t = 1.f - 2.f * e / (1.f + e);
  return x >= 0.f ? t : -t;
}

// ---------------------------------------------------------------------------
// prep 1: C[4096][256] f32 -> Ct[256(h)][4096(f)] fp16, swizzled
__global__ void __launch_bounds__(256) k_transC(const float* __restrict__ C,
                                                _Float16* __restrict__ Ct) {
  __shared__ float sT[64][65];
  const int f0 = blockIdx.x * 64, h0 = blockIdx.y * 64;
  const int t = threadIdx.x;
#pragma unroll
  for (int i = 0; i < 4; ++i) {
    int fl = t + 256 * i;
    int r = fl >> 4, c4 = fl & 15;
    float4 v = *(const float4*)(C + (size_t)(f0 + r) * 256 + h0 + c4 * 4);
    sT[r][c4 * 4 + 0] = v.x; sT[r][c4 * 4 + 1] = v.y;
    sT[r][c4 * 4 + 2] = v.z; sT[r][c4 * 4 + 3] = v.w;
  }
  __syncthreads();
#pragma unroll
  for (int i = 0; i < 2; ++i) {
    int q = t + 256 * i;         // 512 chunks of 8 fp16
    int hr = q >> 3, j = q & 7;  // out row (h), f-chunk within 64
    int h = h0 + hr;
    union { half8 v; _Float16 u[8]; } pk;
#pragma unroll
    for (int u = 0; u < 8; ++u) pk.u[u] = f2h(sT[j * 8 + u][hr]);
    size_t off = (size_t)h * 8192 + (size_t)f0 * 2 + (size_t)((j ^ (h & 7)) << 4);
    *(half8*)((char*)Ct + off) = pk.v;
  }
}

// prep 1b: colsum (deterministic 2-step tree) -> cs[h] = 0.5*sum_f C[f][h]
__global__ void __launch_bounds__(256) k_csum(const float* __restrict__ C,
                                              float* __restrict__ part) {
  const int b = blockIdx.x, t = threadIdx.x;
  float s = 0.f;
  for (int k = 0; k < 256; ++k) s += C[(size_t)(b * 256 + k) * 256 + t];
  part[b * 256 + t] = s;
}
__global__ void __launch_bounds__(256) k_csum2(const float* __restrict__ part,
                                               float* __restrict__ csum) {
  const int t = threadIdx.x;
  float s = 0.f;
#pragma unroll
  for (int b = 0; b < 16; ++b) s += part[b * 256 + t];
  csum[t] = 0.5f * s;
}
// prep 1c: csW[n] = sum_h cs[h]*w_ih[n][h]  (exact fp32 bias correction)
__global__ void __launch_bounds__(256) k_csumW(const float* __restrict__ w_ih,
                                               const float* __restrict__ cs,
                                               float* __restrict__ csW) {
  const int n = blockIdx.x * 256 + threadIdx.x;  // 0..767
  float s = 0.f;
  for (int h = 0; h < 256; ++h) s += cs[h] * w_ih[(size_t)n * 256 + h];
  csW[n] = s;
}

// prep 2: w_ih[768][256] f32 -> Wp[n'=3h+g][256] fp16, swizzled
__global__ void __launch_bounds__(256) k_prepWp(const float* __restrict__ w_ih,
                                                _Float16* __restrict__ Wp) {
  int q = blockIdx.x * 256 + threadIdx.x;  // 24576 chunks
  int row = q >> 5, c = q & 31;
  int seg = c >> 3, j = c & 7;
  int srow = (row % 3) * 256 + row / 3;    // gate-interleave permutation
  const float* src = w_ih + (size_t)srow * 256 + c * 8;
  union { half8 v; _Float16 u[8]; } pk;
#pragma unroll
  for (int u = 0; u < 8; ++u) pk.u[u] = f2h(src[u]);
  size_t off = (size_t)row * 512 + seg * 128 + ((j ^ (row & 7)) << 4);
  *(half8*)((char*)Wp + off) = pk.v;
}

// prep 3: GH[64][768] = h @ w_hh^T + b_hh   (exact fp32)
__global__ void __launch_bounds__(256) k_gh(const float* __restrict__ centers,
                                            const float* __restrict__ w_hh,
                                            const float* __restrict__ b_hh,
                                            float* __restrict__ GH) {
  __shared__ __align__(16) float sH[256];
  const int s = blockIdx.x, t = threadIdx.x;
  sH[t] = centers[(size_t)(s >> 2) * 256 + t];
  __syncthreads();
#pragma unroll
  for (int e = 0; e < 3; ++e) {
    int n = e * 256 + t;
    float accv = b_hh[n];
    const float4* w = (const float4*)(w_hh + (size_t)n * 256);
#pragma unroll 8
    for (int k = 0; k < 64; ++k) {
      float4 v = w[k];
      float4 hh = *(const float4*)&sH[k * 4];
      accv += v.x * hh.x + v.y * hh.y + v.z * hh.z + v.w * hh.w;
    }
    GH[(size_t)s * 768 + n] = accv;
  }
}

// ---------------------------------------------------------------------------
// stage 1: X = (A-0.5) @ C   (fp16 MFMA, fp32 accum).
// BM=64, BN=256, BK=64. grid 256 (1 block/CU), 512 thr (8 waves 2Mx4N).
// Counted-vmcnt pipeline (T3+T4): B triple-buffered, A reg->LDS dbuf,
// ONE barrier per K-step, vmcnt(6) (never 0) in the main loop; prefetch
// issued 2 tiles ahead. Buffer-overwrite safety: stage issues occur after
// barrier k, and barrier k implies every wave finished tile k-1 reads.
__global__ void __launch_bounds__(512) k_stage1(const float* __restrict__ A,
                                                const _Float16* __restrict__ Ct,
                                                _Float16* __restrict__ X) {
  __shared__ __align__(16) _Float16 sA[2][64 * 64];    // 16 KB (dbuf)
  __shared__ __align__(16) _Float16 sB[3][256 * 64];   // 96 KB (3-buf)
  const int t = threadIdx.x;
  const int wid = t >> 6, l = t & 63;
  const int lr = l & 15, lk = l >> 4;
  const int wm = wid >> 2, wn = wid & 3;   // 2M x 4N wave grid
  const int m0 = blockIdx.x * 64;

  f32x4 acc[2][4];
#pragma unroll
  for (int i = 0; i < 2; ++i)
#pragma unroll
    for (int j = 0; j < 4; ++j) acc[i][j] = (f32x4){0.f, 0.f, 0.f, 0.f};

  // A staging: thread t -> row ar (0..63), 8-float chunk aj (0..7)
  const int ar = t >> 3, aj = t & 7;
  const float* aptr = A + (size_t)(m0 + ar) * 4096 + aj * 8;
  const int saw = ar * 128 + ((aj ^ (ar & 7)) << 4);

  // B staging: chunk c = t + 512*i (i<4) -> row c>>3, 8-fp16 chunk c&7;
  // dest linear chunk (source pre-swizzled; copy preserves layout)
  const int br = t >> 3, bj = t & 7;

  // ---- prologue: A(0),A(1) -> regs (NT); B(0)->sB[0], B(1)->sB[1]
  f32x4 t0 = __builtin_nontemporal_load((const f32x4*)(aptr));
  f32x4 t1 = __builtin_nontemporal_load((const f32x4*)(aptr + 4));
  f32x4 p0 = __builtin_nontemporal_load((const f32x4*)(aptr + 64));
  f32x4 p1 = __builtin_nontemporal_load((const f32x4*)(aptr + 64 + 4));
#pragma unroll
  for (int i = 0; i < 4; ++i) {
    size_t so = (size_t)(br + 64 * i) * 4096 + bj * 8;
    int db = (wid * 64 + 512 * i) * 16;
    gload16(Ct + so, (char*)&sB[0][0] + db);
    gload16(Ct + (size_t)64 + so, (char*)&sB[1][0] + db);  // kk=1 -> +64 fp16
  }
  // ds_write A(0) -> sA[0] (compiler inserts the vmcnt wait for t0/t1)
  {
    union { half8 v; _Float16 u[8]; } pk;
    pk.u[0] = f2h(t0.x - 0.5f); pk.u[1] = f2h(t0.y - 0.5f);
    pk.u[2] = f2h(t0.z - 0.5f); pk.u[3] = f2h(t0.w - 0.5f);
    pk.u[4] = f2h(t1.x - 0.5f); pk.u[5] = f2h(t1.y - 0.5f);
    pk.u[6] = f2h(t1.z - 0.5f); pk.u[7] = f2h(t1.w - 0.5f);
    *(half8*)((char*)&sA[0][0] + saw) = pk.v;
  }

  int bcur = 0, bnxt = 2;  // compute buf (kk%3), stage buf ((kk+2)%3)
  for (int kk = 0; kk < 64; ++kk) {
    // B(kk) arrived (mine): leave B(kk+1)[4] + A(kk+1)[2] in flight.
    if (kk < 63) {
      asm volatile("s_waitcnt vmcnt(6)" ::: "memory");
    } else {
      asm volatile("s_waitcnt vmcnt(0)" ::: "memory");
    }
    asm volatile("s_waitcnt lgkmcnt(0)" ::: "memory");  // my A ds_write done
    __builtin_amdgcn_s_barrier();  // A(kk),B(kk) visible to all waves

    // stage 2-ahead: A(kk+2) -> regs (NT), B(kk+2) -> sB[bnxt]
    f32x4 q0, q1;
    if (kk < 62) {
      const float* ap = aptr + (kk + 2) * 64;
      q0 = __builtin_nontemporal_load((const f32x4*)(ap));
      q1 = __builtin_nontemporal_load((const f32x4*)(ap + 4));
#pragma unroll
      for (int i = 0; i < 4; ++i) {
        size_t so = (size_t)(br + 64 * i) * 4096 + (size_t)(kk + 2) * 64 + bj * 8;
        gload16(Ct + so, (char*)&sB[bnxt][0] + (wid * 64 + 512 * i) * 16);
      }
    }
    // ds_write A(kk+1) -> sA[(kk+1)&1] (compiler waits p0/p1 arrival)
    if (kk < 63) {
      union { half8 v; _Float16 u[8]; } pk;
      pk.u[0] = f2h(p0.x - 0.5f); pk.u[1] = f2h(p0.y - 0.5f);
      pk.u[2] = f2h(p0.z - 0.5f); pk.u[3] = f2h(p0.w - 0.5f);
      pk.u[4] = f2h(p1.x - 0.5f); pk.u[5] = f2h(p1.y - 0.5f);
      pk.u[6] = f2h(p1.z - 0.5f); pk.u[7] = f2h(p1.w - 0.5f);
      *(half8*)((char*)&sA[(kk + 1) & 1][0] + saw) = pk.v;
    }

    // compute tile kk from sA[kk&1], sB[bcur]
    const char* pA = (const char*)&sA[kk & 1][0];
    const char* pB = (const char*)&sB[bcur][0];
#pragma unroll
    for (int kc = 0; kc < 2; ++kc) {
      const int q = kc * 4 + lk;
      half8 af[2];
#pragma unroll
      for (int mi = 0; mi < 2; ++mi) {
        int rl = wm * 32 + mi * 16 + lr;
        af[mi] = *(const half8*)(pA + rl * 128 + ((q ^ (rl & 7)) << 4));
      }
#pragma unroll
      for (int ni = 0; ni < 4; ++ni) {
        int rb = wn * 64 + ni * 16 + lr;
        half8 bf = *(const half8*)(pB + rb * 128 + ((q ^ (rb & 7)) << 4));
#pragma unroll
        for (int mi = 0; mi < 2; ++mi)
          acc[mi][ni] = __builtin_amdgcn_mfma_f32_16x16x32_f16(af[mi], bf, acc[mi][ni], 0, 0, 0);
      }
    }
    // no trailing drain; rotate
    if (kk < 62) { p0 = q0; p1 = q1; }
    bcur = (bcur == 2) ? 0 : bcur + 1;
    bnxt = (bnxt == 2) ? 0 : bnxt + 1;
  }

  // epilogue: X -> fp16 (RNE), pre-swizzled storage
#pragma unroll
  for (int mi = 0; mi < 2; ++mi)
#pragma unroll
    for (int ni = 0; ni < 4; ++ni)
#pragma unroll
      for (int p = 0; p < 4; ++p) {
        int m = m0 + wm * 32 + mi * 16 + lk * 4 + p;  // C/D: row=(lane>>4)*4+reg
        int col = wn * 64 + ni * 16 + lr;             //      col=lane&15
        size_t off = (size_t)m * 512 + ((col >> 6) << 7) +
                     ((((col >> 3) & 7) ^ (m & 7)) << 4) + ((col & 7) << 1);
        *(_Float16*)((char*)X + off) = f2h(acc[mi][ni][p]);
      }
}

// ---------------------------------------------------------------------------
// stage 2: GI = X@W (single fp16 pass) + (b_ih + csW) + fused GRU + mean.
// grid 256 (block = batch b), 256 thr, 4 waves 2Mx2N. X panel (32 KB)
// resident in LDS; W tiles (96x256 fp16, 48 KB) staged once per ntile.
// sC (epilogue) aliases the W buffer.
__global__ void __launch_bounds__(256) k_stage2(const _Float16* __restrict__ X,
                                                const _Float16* __restrict__ Wp,
                                                const float* __restrict__ GH,
                                                const float* __restrict__ centers,
                                                const float* __restrict__ b_ih,
                                                const float* __restrict__ csW,
                                                float* __restrict__ out) {
  __shared__ __align__(16) char smem[81920];   // 80 KB
  _Float16* sX = (_Float16*)smem;              // [64][256] fp16 swz : 32 KB
  char*     sW = smem + 32768;                 // [96][256] fp16 swz : 48 KB
  float*    sC = (float*)(smem + 32768);       // [64][100] f32 (aliases sW)
  const int t = threadIdx.x;
  const int wid = t >> 6, l = t & 63;
  const int lr = l & 15, lk = l >> 4;
  const int wm = wid >> 1, wn = wid & 1;
  const int b = blockIdx.x;

  // stage X panel: rows b*64 .. b*64+63 (raw 16B chunks, layout preserved)
#pragma unroll
  for (int i = 0; i < 8; ++i) {
    int flat = t + 256 * i;
    gload16((const char*)X + ((size_t)b * 64 + (flat >> 5)) * 512 +
                (size_t)(flat & 31) * 16,
            (char*)sX + (wid * 64 + 256 * i) * 16);
  }
  __syncthreads();

  for (int nt = 0; nt < 8; ++nt) {
    const int n0 = nt * 96;
    f32x4 acc[2][3];
#pragma unroll
    for (int i = 0; i < 2; ++i)
#pragma unroll
      for (int j = 0; j < 3; ++j) acc[i][j] = (f32x4){0.f, 0.f, 0.f, 0.f};

    // stage W tile 96 x 512B
#pragma unroll
    for (int i = 0; i < 12; ++i) {
      int flat = t + 256 * i;
      gload16((const char*)Wp + (size_t)(n0 + (flat >> 5)) * 512 +
                  (size_t)(flat & 31) * 16,
              sW + (wid * 64 + 256 * i) * 16);
    }
    __syncthreads();  // full drain: W visible
#pragma unroll
    for (int kc = 0; kc < 8; ++kc) {
      const int q = kc * 4 + lk;
      const int seg = (q >> 3) << 7, jj = q & 7;
      half8 af[2];
#pragma unroll
      for (int mi = 0; mi < 2; ++mi) {
        int rl = wm * 32 + mi * 16 + lr;
        af[mi] = *(const half8*)((const char*)sX + rl * 512 + seg + ((jj ^ (rl & 7)) << 4));
      }
#pragma unroll
      for (int ni = 0; ni < 3; ++ni) {
        int rw = wn * 48 + ni * 16 + lr;
        half8 bf = *(const half8*)(sW + rw * 512 + seg + ((jj ^ (rw & 7)) << 4));
#pragma unroll
        for (int mi = 0; mi < 2; ++mi)
          acc[mi][ni] = __builtin_amdgcn_mfma_f32_16x16x32_f16(af[mi], bf, acc[mi][ni], 0, 0, 0);
      }
    }
    __syncthreads();  // all sW reads done before sC alias write
    // acc -> sC (rows = slot s, cols = 3*hl + gate)
#pragma unroll
    for (int mi = 0; mi < 2; ++mi)
#pragma unroll
      for (int ni = 0; ni < 3; ++ni)
#pragma unroll
        for (int p = 0; p < 4; ++p) {
          int row = wm * 32 + mi * 16 + lk * 4 + p;
          int col = wn * 48 + ni * 16 + lr;
          sC[row * 100 + col] = acc[mi][ni][p];
        }
    __syncthreads();
    // fused GRU + level-mean: 16 o x 32 h = 512 items, 2 per thread
#pragma unroll
    for (int ii = 0; ii < 2; ++ii) {
      int item = t + 256 * ii;
      int hl = item & 31, o = item >> 5;
      int h = nt * 32 + hl;
      float hprev = centers[o * 256 + h];
      float bir = b_ih[h] + csW[h];
      float biz = b_ih[256 + h] + csW[256 + h];
      float bin = b_ih[512 + h] + csW[512 + h];
      float sum = 0.f;
#pragma unroll
      for (int j = 0; j < 4; ++j) {
        int s = 4 * o + j;
        float gir = sC[s * 100 + 3 * hl + 0] + bir;
        float giz = sC[s * 100 + 3 * hl + 1] + biz;
        float gin = sC[s * 100 + 3 * hl + 2] + bin;
        float rg = sigmf(gir + GH[s * 768 + h]);
        float zg = sigmf(giz + GH[s * 768 + 256 + h]);
        float ng = tanhf2(gin + rg * GH[s * 768 + 512 + h]);
        sum += (1.f - zg) * ng + zg * hprev;
      }
      out[(size_t)o * 65536 + (size_t)b * 256 + h] = 0.25f * sum;
    }
    __syncthreads();  // sC reads done before next ntile's sW stage (alias)
  }
}

// ---------------------------------------------------------------------------
extern "C" void kernel_launch(void* const* d_in, const int* in_sizes, int n_in,
                              void* d_out, int out_size, void* d_ws, size_t ws_size,
                              hipStream_t stream) {
  (void)in_sizes; (void)n_in; (void)out_size; (void)ws_size;
  const float* attn    = (const float*)d_in[0];  // [256][64][4096]
  const float* centers = (const float*)d_in[1];  // [4096][256]
  const float* w_ih    = (const float*)d_in[2];  // [768][256]
  const float* w_hh    = (const float*)d_in[3];  // [768][256]
  const float* b_ih    = (const float*)d_in[4];  // [768]
  const float* b_hh    = (const float*)d_in[5];  // [768]

  char* ws = (char*)d_ws;
  _Float16* Ct  = (_Float16*)(ws + WS_CT);
  _Float16* Wpp = (_Float16*)(ws + WS_WP);
  float*    GHp = (float*)(ws + WS_GH);
  float*    csp = (float*)(ws + WS_CSP);
  float*    cs  = (float*)(ws + WS_CS);
  float*    csW = (float*)(ws + WS_CSW);
  _Float16* X   = (_Float16*)(ws + WS_X);
  float* out = (float*)d_out;

  hipLaunchKernelGGL(k_transC, dim3(64, 4), dim3(256), 0, stream, centers, Ct);
  hipLaunchKernelGGL(k_csum, dim3(16), dim3(256), 0, stream, centers, csp);
  hipLaunchKernelGGL(k_csum2, dim3(1), dim3(256), 0, stream, csp, cs);
  hipLaunchKernelGGL(k_csumW, dim3(3), dim3(256), 0, stream, w_ih, cs, csW);
  hipLaunchKernelGGL(k_prepWp, dim3(96), dim3(256), 0, stream, w_ih, Wpp);
  hipLaunchKernelGGL(k_gh, dim3(64), dim3(256), 0, stream, centers, w_hh, b_hh, GHp);
  hipLaunchKernelGGL(k_stage1, dim3(256), dim3(512), 0, stream, attn, Ct, X);
  hipLaunchKernelGGL(k_stage2, dim3(256), dim3(256), 0, stream, X, Wpp, GHp, centers, b_ih, csW, out);
}